// Round 1
// baseline (118.875 us; speedup 1.0000x reference)
//
#include <hip/hip_runtime.h>
#include <hip/hip_bf16.h>
#include <math.h>

#define B_N 4096
#define D_N 768
#define C_N 10

typedef float f32x4 __attribute__((ext_vector_type(4)));
typedef unsigned char uchar;

// ws layout (floats):
//   [0] ce_sum   [1] taml_sum   [2] tals   [3] nvalid   [4] done-counter (uint)
//   [8..18)   counts[10]
//   [32..32+7680)  class sums [10][768]
// byte offset 65536: enorm fp8 e4m3 [4096 rows x 768 B]  (3145728 bytes)

typedef __attribute__((address_space(1))) const void gvoid;
typedef __attribute__((address_space(3))) void lvoid;

static __device__ __forceinline__ void gl2lds16(const void* g, void* l) {
    // async global->LDS, 16B per lane, dest = l + lane*16 (wave-uniform l)
    __builtin_amdgcn_global_load_lds((gvoid*)g, (lvoid*)l, 16, 0, 0);
}

// ---------------- merged prep: CE + histogram | class sums | row-normalize->fp8 ----------------
// blocks [0,16): CE; [16,208): class segment sums; [208,1232): enorm (wave/row)
__global__ void k_prep(const float* __restrict__ logits,
                       const int* __restrict__ labels,
                       const float* __restrict__ emb,
                       float* __restrict__ ws,
                       uchar* __restrict__ enorm) {
    __shared__ float red[256];
    __shared__ float cnt[C_N];
    __shared__ float ls[2560];   // CE: one block's 256x10 logits, staged coalesced
    int bb = blockIdx.x;
    int t = threadIdx.x;

    if (bb < 16) {
        if (t < C_N) cnt[t] = 0.f;
        // coalesced float4 staging of this block's logits slice (2560 floats)
        const float4* g4 = (const float4*)logits + bb * 640;
        float4* l4 = (float4*)ls;
        l4[t] = g4[t];
        l4[t + 256] = g4[t + 256];
        if (t < 128) l4[t + 512] = g4[t + 512];
        __syncthreads();
        int row = bb * 256 + t;
        int lab = labels[row];
        const float* lp = ls + t * C_N;   // stride-10 LDS read: 2-way alias, free
        float m = lp[0];
#pragma unroll
        for (int c = 1; c < C_N; ++c) m = fmaxf(m, lp[c]);
        float s = 0.f;
#pragma unroll
        for (int c = 0; c < C_N; ++c) s += __expf(lp[c] - m);
        float val = (m + __logf(s)) - lp[lab];
        atomicAdd(&cnt[lab], 1.0f);
        red[t] = val;
        __syncthreads();
        for (int off = 128; off; off >>= 1) {
            if (t < off) red[t] += red[t + off];
            __syncthreads();
        }
        if (t == 0) atomicAdd(&ws[0], red[0]);
        if (t < C_N) atomicAdd(&ws[8 + t], cnt[t]);
    } else if (bb < 208) {
        int bx = (bb - 16) % 3, by = (bb - 16) / 3;
        int col = bx * 256 + t;
        int rbase = by * 64;
        float a[C_N];
#pragma unroll
        for (int c = 0; c < C_N; ++c) a[c] = 0.f;
        const float* p = emb + (size_t)rbase * D_N + col;
#pragma unroll 4
        for (int rr = 0; rr < 64; ++rr) {
            int lab = labels[rbase + rr];
            float v = p[(size_t)rr * D_N];
#pragma unroll
            for (int c = 0; c < C_N; ++c) a[c] += (lab == c) ? v : 0.f;
        }
        float* sums = ws + 32;
#pragma unroll
        for (int c = 0; c < C_N; ++c) atomicAdd(&sums[c * D_N + col], a[c]);
    } else {
        int w = t >> 6, lane = t & 63;
        int row = (bb - 208) * 4 + w;
        const float4* src = (const float4*)(emb + (size_t)row * D_N);
        float4 x0 = src[lane];
        float4 x1 = src[lane + 64];
        float4 x2 = src[lane + 128];
        float ss = x0.x * x0.x + x0.y * x0.y + x0.z * x0.z + x0.w * x0.w
                 + x1.x * x1.x + x1.y * x1.y + x1.z * x1.z + x1.w * x1.w
                 + x2.x * x2.x + x2.y * x2.y + x2.z * x2.z + x2.w * x2.w;
#pragma unroll
        for (int off = 32; off; off >>= 1) ss += __shfl_xor(ss, off, 64);
        float inv = 1.0f / fmaxf(sqrtf(ss), 1e-12f);
        int p0 = 0, p1 = 0, p2 = 0;
        p0 = __builtin_amdgcn_cvt_pk_fp8_f32(x0.x * inv, x0.y * inv, p0, false);
        p0 = __builtin_amdgcn_cvt_pk_fp8_f32(x0.z * inv, x0.w * inv, p0, true);
        p1 = __builtin_amdgcn_cvt_pk_fp8_f32(x1.x * inv, x1.y * inv, p1, false);
        p1 = __builtin_amdgcn_cvt_pk_fp8_f32(x1.z * inv, x1.w * inv, p1, true);
        p2 = __builtin_amdgcn_cvt_pk_fp8_f32(x2.x * inv, x2.y * inv, p2, false);
        p2 = __builtin_amdgcn_cvt_pk_fp8_f32(x2.z * inv, x2.w * inv, p2, true);
        unsigned int* dst = (unsigned int*)(enorm + (size_t)row * D_N);
        dst[lane]       = (unsigned int)p0;
        dst[lane + 64]  = (unsigned int)p1;
        dst[lane + 128] = (unsigned int)p2;
    }
}

// last-block-done: every one of the 1024 blocks calls this exactly once at its end.
// The 1024th arrival computes the final combined output (replaces k_final).
static __device__ __forceinline__ void finish(float* __restrict__ ws,
                                              float* __restrict__ out, int t) {
    if (t == 0) {
        __threadfence();   // release this block's ws writes device-wide
        unsigned int prev = atomicAdd((unsigned int*)ws + 4, 1u);
        if (prev == 1023u) {
            __threadfence();   // acquire all other blocks' released writes
            float ces  = atomicAdd(&ws[0], 0.0f);   // device-scope reads
            float tsum = atomicAdd(&ws[1], 0.0f);
            float tals = atomicAdd(&ws[2], 0.0f);
            float nv   = atomicAdd(&ws[3], 0.0f);
            float ce   = ces / (float)B_N;
            float taml = tsum / fmaxf(nv, 1.0f);
            out[0] = ce + 0.5f * tals + 0.5f * taml;
            out[1] = ce;
            out[2] = tals;
            out[3] = taml;
        }
    }
}

// ---------------- fused TAML GEMM (fp8, BK=128) + TALS in an idle helper block ----------------
// 128x128 tile, BK=128 (row = 128 B fp8), double-buffered LDS (2 x 16KB per side,
// 64KB -> 2 blocks/CU), async global_load_lds 16B, ONE barrier per K-iter AFTER
// compute: 64 MFMAs cover each pre-barrier vmcnt drain. 3-bit XOR slot swizzle
// (R8-verified): DMA lane fetches global 16B-slot (cs^rl) -> LDS slot cs;
// fragment read of global slot s of row r comes from LDS slot s^(r&7).
__global__ __launch_bounds__(256) void k_taml(const uchar* __restrict__ E,
                                              const int* __restrict__ labels,
                                              const float* __restrict__ topo,
                                              float* __restrict__ ws,
                                              float* __restrict__ out) {
    __shared__ __align__(16) uchar As[2][16384];
    __shared__ __align__(16) uchar Bs[2][16384];
    __shared__ int lA[128], lB[128];
    __shared__ float topo_s[C_N * C_N];
    __shared__ float wsum[4];
    __shared__ float ed[112];
    __shared__ float cnt_s[C_N];

    int bi = blockIdx.y, bj = blockIdx.x;
    int t = threadIdx.x;
    int w = t >> 6, lane = t & 63;

    if (bj < bi) {
        // ---- idle helper block computes TALS (k_prep outputs are ready) ----
        if (bi == 1 && bj == 0) {
            float* cents = (float*)&As[0][0];   // 30 KB scratch
            const float* sums = ws + 32;
            if (t < C_N) cnt_s[t] = ws[8 + t];
            __syncthreads();
            for (int idx = t; idx < C_N * D_N; idx += 256) {
                int c = idx / D_N;
                cents[idx] = sums[idx] / fmaxf(cnt_s[c], 1.0f);
            }
            __syncthreads();
            for (int pp = 0; pp < 25; ++pp) {   // 100 pairs; wave w: 25w..25w+24
                int p = w * 25 + pp;
                int i = p / C_N, j = p - (p / C_N) * C_N;
                const float* ci = cents + i * D_N;
                const float* cj = cents + j * D_N;
                float s = 0.f;
                for (int d = lane; d < D_N; d += 64) {
                    float diff = ci[d] - cj[d];
                    s += diff * diff;
                }
#pragma unroll
                for (int off = 32; off; off >>= 1) s += __shfl_xor(s, off, 64);
                if (lane == 0) ed[p] = sqrtf(s + 1e-12f);
            }
            __syncthreads();
            if (w == 0) {
                float e0 = ed[lane];
                float e1 = (lane < 36) ? ed[lane + 64] : 0.f;
                float mx = fmaxf(e0, e1);
#pragma unroll
                for (int off = 32; off; off >>= 1) mx = fmaxf(mx, __shfl_xor(mx, off, 64));
                float inv = 1.0f / (mx + 1e-8f);
                float d0 = e0 * inv - topo[lane];
                float s = d0 * d0;
                if (lane < 36) {
                    float d1 = e1 * inv - topo[lane + 64];
                    s += d1 * d1;
                }
#pragma unroll
                for (int off = 32; off; off >>= 1) s += __shfl_xor(s, off, 64);
                if (lane == 0) {
                    ws[2] = s * (1.0f / (C_N * C_N));
                    float s2 = 0.f;
#pragma unroll
                    for (int c = 0; c < C_N; ++c) s2 += cnt_s[c] * cnt_s[c];
                    ws[3] = (float)B_N * (float)B_N - s2;
                }
            }
        }
        finish(ws, out, t);
        return;
    }

    int ib0 = bi * 128, jb0 = bj * 128;
    if (t < 128) lA[t] = labels[ib0 + t];
    else         lB[t - 128] = labels[jb0 + t - 128];
    if (t < C_N * C_N) topo_s[t] = topo[t];

    int quad = lane >> 4, m16 = lane & 15;
    int wrow = (w >> 1) * 64, wcol = (w & 1) * 64;

    f32x4 acc[4][4];
    f32x4 z = {0.f, 0.f, 0.f, 0.f};
#pragma unroll
    for (int mt = 0; mt < 4; ++mt)
#pragma unroll
        for (int nt = 0; nt < 4; ++nt) acc[mt][nt] = z;

    // staging: 16 chunks of 1KB per tile side (chunk = 8 rows x 128 B).
    // wave w owns chunks {w, w+4, w+8, w+12} per side. lane: rl = lane>>3 (row
    // in chunk), cs = lane&7 (16B slot); fetch global slot cs^rl -> LDS slot cs.
    int rl = lane >> 3, cs = lane & 7;
    int csw = (cs ^ rl) * 16;   // byte offset within the 128B row
    const uchar* gA[4];
    const uchar* gB[4];
    int ldsoff[4];
#pragma unroll
    for (int h = 0; h < 4; ++h) {
        int chunk = w + 4 * h;
        gA[h] = E + (size_t)(ib0 + chunk * 8 + rl) * D_N + csw;
        gB[h] = E + (size_t)(jb0 + chunk * 8 + rl) * D_N + csw;
        ldsoff[h] = chunk * 1024;
    }

    // prologue: tile 0 -> buffer 0
#pragma unroll
    for (int h = 0; h < 4; ++h) {
        gl2lds16(gA[h], &As[0][ldsoff[h]]);
        gl2lds16(gB[h], &Bs[0][ldsoff[h]]);
    }
    __syncthreads();   // drain tile0; also covers lA/lB/topo_s

    for (int kt = 0; kt < 6; ++kt) {
        int cur = kt & 1, nxt = cur ^ 1;
        if (kt < 5) {
#pragma unroll
            for (int h = 0; h < 4; ++h) {
                gl2lds16(gA[h] + (kt + 1) * 128, &As[nxt][ldsoff[h]]);
                gl2lds16(gB[h] + (kt + 1) * 128, &Bs[nxt][ldsoff[h]]);
            }
        }
#pragma unroll
        for (int ks = 0; ks < 4; ++ks) {
            int s = ks * 2 + (quad >> 1);   // 16B slot of this k-octet
            int in8 = (quad & 1) * 8;       // 8B half within the slot
            long af[4], bfr[4];
#pragma unroll
            for (int x = 0; x < 4; ++x) {
                int rowA = wrow + x * 16 + m16;
                int rowB = wcol + x * 16 + m16;
                af[x]  = *(const long*)(&As[cur][rowA * 128 + ((s ^ (rowA & 7)) * 16) + in8]);
                bfr[x] = *(const long*)(&Bs[cur][rowB * 128 + ((s ^ (rowB & 7)) * 16) + in8]);
            }
#pragma unroll
            for (int mt = 0; mt < 4; ++mt)
#pragma unroll
                for (int nt = 0; nt < 4; ++nt)
                    acc[mt][nt] = __builtin_amdgcn_mfma_f32_16x16x32_fp8_fp8(
                        af[mt], bfr[nt], acc[mt][nt], 0, 0, 0);
        }
        __syncthreads();   // drain of next-tile loads happens AFTER compute
    }

    // epilogue: relu(sim - 1 + margin) over valid (li!=lj) upper-tri pairs, x2
    float local = 0.f;
#pragma unroll
    for (int mt = 0; mt < 4; ++mt) {
#pragma unroll
        for (int nt = 0; nt < 4; ++nt) {
#pragma unroll
            for (int reg = 0; reg < 4; ++reg) {
                int il = wrow + mt * 16 + quad * 4 + reg;
                int jl = wcol + nt * 16 + m16;
                int gi = ib0 + il, gj = jb0 + jl;
                int li = lA[il], lj = lB[jl];
                float v = acc[mt][nt][reg] - 1.0f + topo_s[li * C_N + lj];
                if (li != lj && gi < gj && v > 0.f) local += v;
            }
        }
    }
    local *= 2.0f;

#pragma unroll
    for (int off = 32; off; off >>= 1) local += __shfl_down(local, off, 64);
    if (lane == 0) wsum[w] = local;
    __syncthreads();
    if (t == 0) atomicAdd(&ws[1], wsum[0] + wsum[1] + wsum[2] + wsum[3]);
    finish(ws, out, t);
}

extern "C" void kernel_launch(void* const* d_in, const int* in_sizes, int n_in,
                              void* d_out, int out_size, void* d_ws, size_t ws_size,
                              hipStream_t stream) {
    const float* logits = (const float*)d_in[0];
    const int*   labels = (const int*)d_in[1];
    const float* emb    = (const float*)d_in[2];
    const float* topo   = (const float*)d_in[3];
    float* ws = (float*)d_ws;
    uchar* enorm = (uchar*)d_ws + 65536;
    float* out = (float*)d_out;

    hipMemsetAsync(d_ws, 0, 31232, stream);
    k_prep<<<1232, 256, 0, stream>>>(logits, labels, emb, ws, enorm);
    k_taml<<<dim3(32, 32), 256, 0, stream>>>(enorm, labels, topo, ws, out);
}

// Round 2
// 108.441 us; speedup vs baseline: 1.0962x; 1.0962x over previous
//
#include <hip/hip_runtime.h>
#include <hip/hip_bf16.h>
#include <math.h>

#define B_N 4096
#define D_N 768
#define C_N 10

typedef float f32x4 __attribute__((ext_vector_type(4)));
typedef unsigned char uchar;

// ws layout (floats):
//   [0] ce_sum   [1] taml_sum   [2] tals   [3] nvalid
//   [8..18)   counts[10]
//   [32..32+7680)  class sums [10][768]
//   [7744] done-counter (uint, cold line)
// byte offset 65536: enorm fp8 e4m3 [4096 rows x 768 B]  (3145728 bytes)

typedef __attribute__((address_space(1))) const void gvoid;
typedef __attribute__((address_space(3))) void lvoid;

static __device__ __forceinline__ void gl2lds16(const void* g, void* l) {
    // async global->LDS, 16B per lane, dest = l + lane*16 (wave-uniform l)
    __builtin_amdgcn_global_load_lds((gvoid*)g, (lvoid*)l, 16, 0, 0);
}

// ---------------- merged prep: CE + histogram | class sums | row-normalize->fp8 ----------------
// blocks [0,16): CE; [16,208): class segment sums; [208,1232): enorm (wave/row)
__global__ void k_prep(const float* __restrict__ logits,
                       const int* __restrict__ labels,
                       const float* __restrict__ emb,
                       float* __restrict__ ws,
                       uchar* __restrict__ enorm) {
    __shared__ float red[256];
    __shared__ float cnt[C_N];
    __shared__ float ls[2560];   // CE: one block's 256x10 logits, staged coalesced
    int bb = blockIdx.x;
    int t = threadIdx.x;

    if (bb < 16) {
        if (t < C_N) cnt[t] = 0.f;
        // coalesced float4 staging of this block's logits slice (2560 floats)
        const float4* g4 = (const float4*)logits + bb * 640;
        float4* l4 = (float4*)ls;
        l4[t] = g4[t];
        l4[t + 256] = g4[t + 256];
        if (t < 128) l4[t + 512] = g4[t + 512];
        __syncthreads();
        int row = bb * 256 + t;
        int lab = labels[row];
        const float* lp = ls + t * C_N;   // stride-10 LDS read: 2-way alias, free
        float m = lp[0];
#pragma unroll
        for (int c = 1; c < C_N; ++c) m = fmaxf(m, lp[c]);
        float s = 0.f;
#pragma unroll
        for (int c = 0; c < C_N; ++c) s += __expf(lp[c] - m);
        float val = (m + __logf(s)) - lp[lab];
        atomicAdd(&cnt[lab], 1.0f);
        red[t] = val;
        __syncthreads();
        for (int off = 128; off; off >>= 1) {
            if (t < off) red[t] += red[t + off];
            __syncthreads();
        }
        if (t == 0) atomicAdd(&ws[0], red[0]);
        if (t < C_N) atomicAdd(&ws[8 + t], cnt[t]);
    } else if (bb < 208) {
        int bx = (bb - 16) % 3, by = (bb - 16) / 3;
        int col = bx * 256 + t;
        int rbase = by * 64;
        float a[C_N];
#pragma unroll
        for (int c = 0; c < C_N; ++c) a[c] = 0.f;
        const float* p = emb + (size_t)rbase * D_N + col;
#pragma unroll 4
        for (int rr = 0; rr < 64; ++rr) {
            int lab = labels[rbase + rr];
            float v = p[(size_t)rr * D_N];
#pragma unroll
            for (int c = 0; c < C_N; ++c) a[c] += (lab == c) ? v : 0.f;
        }
        float* sums = ws + 32;
#pragma unroll
        for (int c = 0; c < C_N; ++c) atomicAdd(&sums[c * D_N + col], a[c]);
    } else {
        int w = t >> 6, lane = t & 63;
        int row = (bb - 208) * 4 + w;
        const float4* src = (const float4*)(emb + (size_t)row * D_N);
        float4 x0 = src[lane];
        float4 x1 = src[lane + 64];
        float4 x2 = src[lane + 128];
        float ss = x0.x * x0.x + x0.y * x0.y + x0.z * x0.z + x0.w * x0.w
                 + x1.x * x1.x + x1.y * x1.y + x1.z * x1.z + x1.w * x1.w
                 + x2.x * x2.x + x2.y * x2.y + x2.z * x2.z + x2.w * x2.w;
#pragma unroll
        for (int off = 32; off; off >>= 1) ss += __shfl_xor(ss, off, 64);
        float inv = 1.0f / fmaxf(sqrtf(ss), 1e-12f);
        int p0 = 0, p1 = 0, p2 = 0;
        p0 = __builtin_amdgcn_cvt_pk_fp8_f32(x0.x * inv, x0.y * inv, p0, false);
        p0 = __builtin_amdgcn_cvt_pk_fp8_f32(x0.z * inv, x0.w * inv, p0, true);
        p1 = __builtin_amdgcn_cvt_pk_fp8_f32(x1.x * inv, x1.y * inv, p1, false);
        p1 = __builtin_amdgcn_cvt_pk_fp8_f32(x1.z * inv, x1.w * inv, p1, true);
        p2 = __builtin_amdgcn_cvt_pk_fp8_f32(x2.x * inv, x2.y * inv, p2, false);
        p2 = __builtin_amdgcn_cvt_pk_fp8_f32(x2.z * inv, x2.w * inv, p2, true);
        unsigned int* dst = (unsigned int*)(enorm + (size_t)row * D_N);
        dst[lane]       = (unsigned int)p0;
        dst[lane + 64]  = (unsigned int)p1;
        dst[lane + 128] = (unsigned int)p2;
    }
}

// last-block-done: all 529 blocks call this once at their END (staggered in time,
// so the contended counter never forms a queue like the round-1 start-of-kernel storm).
static __device__ __forceinline__ void finish(float* __restrict__ ws,
                                              float* __restrict__ out, int t) {
    if (t == 0) {
        __threadfence();   // release this block's ws writes device-wide
        unsigned int prev = atomicAdd((unsigned int*)ws + 7744, 1u);
        if (prev == 528u) {
            __threadfence();   // acquire all other blocks' released writes
            float ces  = atomicAdd(&ws[0], 0.0f);   // device-scope reads
            float tsum = atomicAdd(&ws[1], 0.0f);
            float tals = atomicAdd(&ws[2], 0.0f);
            float nv   = atomicAdd(&ws[3], 0.0f);
            float ce   = ces / (float)B_N;
            float taml = tsum / fmaxf(nv, 1.0f);
            out[0] = ce + 0.5f * tals + 0.5f * taml;
            out[1] = ce;
            out[2] = tals;
            out[3] = taml;
        }
    }
}

// ---------------- fused TAML GEMM (fp8, BK=64) + TALS in block 0 ----------------
// 1D grid of 529 blocks: id 0 = TALS helper; id 1..528 = upper-tri 128x128 tiles.
// BK=64: LDS = 4 x 8KB (A/B double-buffered) = 32KB (+~2KB small) -> 4 blocks/CU.
// Swizzle (re-derived for 64B rows): global 16B-slot g of row r lives at LDS slot
// g ^ ((r>>1)&3). DMA lane (rl=lane>>2, cs=lane&3) fetches global slot cs^((rl>>1)&3)
// into linear LDS slot cs. Fragment ds_read_b64 of 16 lanes then spans 8 distinct
// (row-parity, slot) bank groups -> 2-way alias = free.
__global__ __launch_bounds__(256) void k_taml(const uchar* __restrict__ E,
                                              const int* __restrict__ labels,
                                              const float* __restrict__ topo,
                                              float* __restrict__ ws,
                                              float* __restrict__ out) {
    __shared__ __align__(16) uchar smem[32768];   // A: [0,16K) bufs 0/1; B: [16K,32K)
    __shared__ int lA[128], lB[128];
    __shared__ float topo_s[C_N * C_N];
    __shared__ float wsum[4];
    __shared__ float ed[112];
    __shared__ float cnt_s[C_N];

    int t = threadIdx.x;
    int w = t >> 6, lane = t & 63;
    int id = blockIdx.x;

    if (id == 0) {
        // ---- TALS (k_prep outputs ready via stream order) ----
        float* cents = (float*)smem;   // 30 KB scratch
        const float* sums = ws + 32;
        if (t < C_N) cnt_s[t] = ws[8 + t];
        __syncthreads();
        for (int idx = t; idx < C_N * D_N; idx += 256) {
            int c = idx / D_N;
            cents[idx] = sums[idx] / fmaxf(cnt_s[c], 1.0f);
        }
        __syncthreads();
        for (int pp = 0; pp < 25; ++pp) {   // 100 pairs; wave w: 25w..25w+24
            int p = w * 25 + pp;
            int i = p / C_N, j = p - (p / C_N) * C_N;
            const float* ci = cents + i * D_N;
            const float* cj = cents + j * D_N;
            float s = 0.f;
            for (int d = lane; d < D_N; d += 64) {
                float diff = ci[d] - cj[d];
                s += diff * diff;
            }
#pragma unroll
            for (int off = 32; off; off >>= 1) s += __shfl_xor(s, off, 64);
            if (lane == 0) ed[p] = sqrtf(s + 1e-12f);
        }
        __syncthreads();
        if (w == 0) {
            float e0 = ed[lane];
            float e1 = (lane < 36) ? ed[lane + 64] : 0.f;
            float mx = fmaxf(e0, e1);
#pragma unroll
            for (int off = 32; off; off >>= 1) mx = fmaxf(mx, __shfl_xor(mx, off, 64));
            float inv = 1.0f / (mx + 1e-8f);
            float d0 = e0 * inv - topo[lane];
            float s = d0 * d0;
            if (lane < 36) {
                float d1 = e1 * inv - topo[lane + 64];
                s += d1 * d1;
            }
#pragma unroll
            for (int off = 32; off; off >>= 1) s += __shfl_xor(s, off, 64);
            if (lane == 0) {
                ws[2] = s * (1.0f / (C_N * C_N));
                float s2 = 0.f;
#pragma unroll
                for (int c = 0; c < C_N; ++c) s2 += cnt_s[c] * cnt_s[c];
                ws[3] = (float)B_N * (float)B_N - s2;
            }
        }
        finish(ws, out, t);
        return;
    }

    // triangle decode: id-1 -> (bi, bj) with bj >= bi, bi-major
    int u = id - 1, bi = 0, rowlen = 32;
    while (u >= rowlen) { u -= rowlen; ++bi; --rowlen; }
    int bj = bi + u;

    int ib0 = bi * 128, jb0 = bj * 128;
    if (t < 128) lA[t] = labels[ib0 + t];
    else         lB[t - 128] = labels[jb0 + t - 128];
    if (t < C_N * C_N) topo_s[t] = topo[t];

    int quad = lane >> 4, m16 = lane & 15;
    int wrow = (w >> 1) * 64, wcol = (w & 1) * 64;

    f32x4 acc[4][4];
    f32x4 z = {0.f, 0.f, 0.f, 0.f};
#pragma unroll
    for (int mt = 0; mt < 4; ++mt)
#pragma unroll
        for (int nt = 0; nt < 4; ++nt) acc[mt][nt] = z;

    // staging: 8 chunks of 1KB per tile side (chunk = 16 rows x 64 B).
    // wave w owns chunks {w, w+4} per side.
    int rl = lane >> 2, cs = lane & 3;
    int csw = (cs ^ ((rl >> 1) & 3)) * 16;   // pre-swizzled global 16B slot
    const uchar* gA[2];
    const uchar* gB[2];
    int ldsoff[2];
#pragma unroll
    for (int h = 0; h < 2; ++h) {
        int chunk = w + 4 * h;
        gA[h] = E + (size_t)(ib0 + chunk * 16 + rl) * D_N + csw;
        gB[h] = E + (size_t)(jb0 + chunk * 16 + rl) * D_N + csw;
        ldsoff[h] = chunk * 1024;
    }

    // prologue: K-window 0 -> buffer 0
#pragma unroll
    for (int h = 0; h < 2; ++h) {
        gl2lds16(gA[h], smem + ldsoff[h]);
        gl2lds16(gB[h], smem + 16384 + ldsoff[h]);
    }
    __syncthreads();   // drain window0; also covers lA/lB/topo_s

    for (int kt = 0; kt < 12; ++kt) {
        int cur = kt & 1, nxt = cur ^ 1;
        if (kt < 11) {
#pragma unroll
            for (int h = 0; h < 2; ++h) {
                gl2lds16(gA[h] + (kt + 1) * 64, smem + (nxt << 13) + ldsoff[h]);
                gl2lds16(gB[h] + (kt + 1) * 64, smem + 16384 + (nxt << 13) + ldsoff[h]);
            }
        }
        const uchar* Ac = smem + (cur << 13);
        const uchar* Bc = smem + 16384 + (cur << 13);
#pragma unroll
        for (int ks = 0; ks < 2; ++ks) {
            int s = ks * 2 + (quad >> 1);   // 16B slot of this k-octet
            int in8 = (quad & 1) * 8;       // 8B half within the slot
            long af[4], bfr[4];
#pragma unroll
            for (int x = 0; x < 4; ++x) {
                int rowA = wrow + x * 16 + m16;
                int rowB = wcol + x * 16 + m16;
                af[x]  = *(const long*)(Ac + rowA * 64 + ((s ^ ((rowA >> 1) & 3)) * 16) + in8);
                bfr[x] = *(const long*)(Bc + rowB * 64 + ((s ^ ((rowB >> 1) & 3)) * 16) + in8);
            }
#pragma unroll
            for (int mt = 0; mt < 4; ++mt)
#pragma unroll
                for (int nt = 0; nt < 4; ++nt)
                    acc[mt][nt] = __builtin_amdgcn_mfma_f32_16x16x32_fp8_fp8(
                        af[mt], bfr[nt], acc[mt][nt], 0, 0, 0);
        }
        __syncthreads();   // drain of next-window loads happens AFTER compute
    }

    // epilogue: relu(sim - 1 + margin) over valid (li!=lj) upper-tri pairs, x2
    float local = 0.f;
#pragma unroll
    for (int mt = 0; mt < 4; ++mt) {
#pragma unroll
        for (int nt = 0; nt < 4; ++nt) {
#pragma unroll
            for (int reg = 0; reg < 4; ++reg) {
                int il = wrow + mt * 16 + quad * 4 + reg;
                int jl = wcol + nt * 16 + m16;
                int gi = ib0 + il, gj = jb0 + jl;
                int li = lA[il], lj = lB[jl];
                float v = acc[mt][nt][reg] - 1.0f + topo_s[li * C_N + lj];
                if (li != lj && gi < gj && v > 0.f) local += v;
            }
        }
    }
    local *= 2.0f;

#pragma unroll
    for (int off = 32; off; off >>= 1) local += __shfl_down(local, off, 64);
    if (lane == 0) wsum[w] = local;
    __syncthreads();
    if (t == 0) atomicAdd(&ws[1], wsum[0] + wsum[1] + wsum[2] + wsum[3]);
    finish(ws, out, t);
}

extern "C" void kernel_launch(void* const* d_in, const int* in_sizes, int n_in,
                              void* d_out, int out_size, void* d_ws, size_t ws_size,
                              hipStream_t stream) {
    const float* logits = (const float*)d_in[0];
    const int*   labels = (const int*)d_in[1];
    const float* emb    = (const float*)d_in[2];
    const float* topo   = (const float*)d_in[3];
    float* ws = (float*)d_ws;
    uchar* enorm = (uchar*)d_ws + 65536;
    float* out = (float*)d_out;

    hipMemsetAsync(d_ws, 0, 31232, stream);
    k_prep<<<1232, 256, 0, stream>>>(logits, labels, emb, ws, enorm);
    k_taml<<<529, 256, 0, stream>>>(enorm, labels, topo, ws, out);
}

// Round 3
// 106.478 us; speedup vs baseline: 1.1164x; 1.0184x over previous
//
#include <hip/hip_runtime.h>
#include <hip/hip_bf16.h>
#include <math.h>

#define B_N 4096
#define D_N 768
#define C_N 10

typedef float f32x4 __attribute__((ext_vector_type(4)));
typedef unsigned char uchar;

// ws layout (floats):
//   [0] ce_sum   [2] tals   [3] nvalid
//   [8..18)   counts[10]
//   [20..28)  taml partial sums (8 slots, contention-spread)
//   [32..32+7680)  class sums [10][768]
// byte offset 65536: enorm fp8 e4m3 [4096 rows x 768 B]  (3145728 bytes)

typedef __attribute__((address_space(1))) const void gvoid;
typedef __attribute__((address_space(3))) void lvoid;

static __device__ __forceinline__ void gl2lds16(const void* g, void* l) {
    // async global->LDS, 16B per lane, dest = l + lane*16 (wave-uniform l)
    __builtin_amdgcn_global_load_lds((gvoid*)g, (lvoid*)l, 16, 0, 0);
}

// ---------------- merged prep: CE + histogram | class sums | row-normalize->fp8 ----------------
// blocks [0,16): CE; [16,208): class segment sums; [208,1232): enorm (wave/row)
__global__ void k_prep(const float* __restrict__ logits,
                       const int* __restrict__ labels,
                       const float* __restrict__ emb,
                       float* __restrict__ ws,
                       uchar* __restrict__ enorm) {
    __shared__ float red[256];
    __shared__ float cnt[C_N];
    __shared__ float ls[2560];   // CE: one block's 256x10 logits, staged coalesced
    int bb = blockIdx.x;
    int t = threadIdx.x;

    if (bb < 16) {
        if (t < C_N) cnt[t] = 0.f;
        // coalesced float4 staging of this block's logits slice (2560 floats)
        const float4* g4 = (const float4*)logits + bb * 640;
        float4* l4 = (float4*)ls;
        l4[t] = g4[t];
        l4[t + 256] = g4[t + 256];
        if (t < 128) l4[t + 512] = g4[t + 512];
        __syncthreads();
        int row = bb * 256 + t;
        int lab = labels[row];
        const float* lp = ls + t * C_N;   // stride-10 LDS read: 2-way alias, free
        float m = lp[0];
#pragma unroll
        for (int c = 1; c < C_N; ++c) m = fmaxf(m, lp[c]);
        float s = 0.f;
#pragma unroll
        for (int c = 0; c < C_N; ++c) s += __expf(lp[c] - m);
        float val = (m + __logf(s)) - lp[lab];
        atomicAdd(&cnt[lab], 1.0f);
        red[t] = val;
        __syncthreads();
        for (int off = 128; off; off >>= 1) {
            if (t < off) red[t] += red[t + off];
            __syncthreads();
        }
        if (t == 0) atomicAdd(&ws[0], red[0]);
        if (t < C_N) atomicAdd(&ws[8 + t], cnt[t]);
    } else if (bb < 208) {
        int bx = (bb - 16) % 3, by = (bb - 16) / 3;
        int col = bx * 256 + t;
        int rbase = by * 64;
        float a[C_N];
#pragma unroll
        for (int c = 0; c < C_N; ++c) a[c] = 0.f;
        const float* p = emb + (size_t)rbase * D_N + col;
#pragma unroll 4
        for (int rr = 0; rr < 64; ++rr) {
            int lab = labels[rbase + rr];
            float v = p[(size_t)rr * D_N];
#pragma unroll
            for (int c = 0; c < C_N; ++c) a[c] += (lab == c) ? v : 0.f;
        }
        float* sums = ws + 32;
#pragma unroll
        for (int c = 0; c < C_N; ++c) atomicAdd(&sums[c * D_N + col], a[c]);
    } else {
        int w = t >> 6, lane = t & 63;
        int row = (bb - 208) * 4 + w;
        const float4* src = (const float4*)(emb + (size_t)row * D_N);
        float4 x0 = src[lane];
        float4 x1 = src[lane + 64];
        float4 x2 = src[lane + 128];
        float ss = x0.x * x0.x + x0.y * x0.y + x0.z * x0.z + x0.w * x0.w
                 + x1.x * x1.x + x1.y * x1.y + x1.z * x1.z + x1.w * x1.w
                 + x2.x * x2.x + x2.y * x2.y + x2.z * x2.z + x2.w * x2.w;
#pragma unroll
        for (int off = 32; off; off >>= 1) ss += __shfl_xor(ss, off, 64);
        float inv = 1.0f / fmaxf(sqrtf(ss), 1e-12f);
        int p0 = 0, p1 = 0, p2 = 0;
        p0 = __builtin_amdgcn_cvt_pk_fp8_f32(x0.x * inv, x0.y * inv, p0, false);
        p0 = __builtin_amdgcn_cvt_pk_fp8_f32(x0.z * inv, x0.w * inv, p0, true);
        p1 = __builtin_amdgcn_cvt_pk_fp8_f32(x1.x * inv, x1.y * inv, p1, false);
        p1 = __builtin_amdgcn_cvt_pk_fp8_f32(x1.z * inv, x1.w * inv, p1, true);
        p2 = __builtin_amdgcn_cvt_pk_fp8_f32(x2.x * inv, x2.y * inv, p2, false);
        p2 = __builtin_amdgcn_cvt_pk_fp8_f32(x2.z * inv, x2.w * inv, p2, true);
        unsigned int* dst = (unsigned int*)(enorm + (size_t)row * D_N);
        dst[lane]       = (unsigned int)p0;
        dst[lane + 64]  = (unsigned int)p1;
        dst[lane + 128] = (unsigned int)p2;
    }
}

// ---------------- fused TAML GEMM (fp8, BK=64, 3-deep counted-vmcnt pipeline) ----------------
// 1D grid of 529 blocks: id 0 = TALS helper; id 1..528 = upper-tri 128x128 tiles.
// LDS: A = 3 x 8KB at [0,24K), B = 3 x 8KB at [24K,48K) -> ~50KB total -> 3 blocks/CU.
// Pipeline: prologue issues K-windows 0..2; iter kt waits s_waitcnt vmcnt(8)
// (= window kt's 4 per-thread DMAs complete, windows kt+1/kt+2 stay in flight),
// raw s_barrier, compute, raw s_barrier, issue window kt+3 into the freed buffer.
// NO vmcnt(0) drain in the main loop (T3/T4).
// Swizzle (64B rows): global 16B-slot g of row r lives at LDS slot g ^ ((r>>1)&3).
// DMA lane (rl=lane>>2, cs=lane&3) fetches global slot cs^((rl>>1)&3) into linear
// LDS slot cs; fragment read applies the same XOR -> 2-way alias = free.
__global__ __launch_bounds__(256) void k_taml(const uchar* __restrict__ E,
                                              const int* __restrict__ labels,
                                              const float* __restrict__ topo,
                                              float* __restrict__ ws) {
    __shared__ __align__(16) uchar smem[49152];
    __shared__ int lA[128], lB[128];
    __shared__ float topo_s[C_N * C_N];
    __shared__ float wsum[4];
    __shared__ float ed[112];
    __shared__ float cnt_s[C_N];

    int t = threadIdx.x;
    int w = t >> 6, lane = t & 63;
    int id = blockIdx.x;

    if (id == 0) {
        // ---- TALS (k_prep outputs ready via stream order) ----
        float* cents = (float*)smem;   // 30 KB scratch
        const float* sums = ws + 32;
        if (t < C_N) cnt_s[t] = ws[8 + t];
        __syncthreads();
        for (int idx = t; idx < C_N * D_N; idx += 256) {
            int c = idx / D_N;
            cents[idx] = sums[idx] / fmaxf(cnt_s[c], 1.0f);
        }
        __syncthreads();
        for (int pp = 0; pp < 25; ++pp) {   // 100 pairs; wave w: 25w..25w+24
            int p = w * 25 + pp;
            int i = p / C_N, j = p - (p / C_N) * C_N;
            const float* ci = cents + i * D_N;
            const float* cj = cents + j * D_N;
            float s = 0.f;
            for (int d = lane; d < D_N; d += 64) {
                float diff = ci[d] - cj[d];
                s += diff * diff;
            }
#pragma unroll
            for (int off = 32; off; off >>= 1) s += __shfl_xor(s, off, 64);
            if (lane == 0) ed[p] = sqrtf(s + 1e-12f);
        }
        __syncthreads();
        if (w == 0) {
            float e0 = ed[lane];
            float e1 = (lane < 36) ? ed[lane + 64] : 0.f;
            float mx = fmaxf(e0, e1);
#pragma unroll
            for (int off = 32; off; off >>= 1) mx = fmaxf(mx, __shfl_xor(mx, off, 64));
            float inv = 1.0f / (mx + 1e-8f);
            float d0 = e0 * inv - topo[lane];
            float s = d0 * d0;
            if (lane < 36) {
                float d1 = e1 * inv - topo[lane + 64];
                s += d1 * d1;
            }
#pragma unroll
            for (int off = 32; off; off >>= 1) s += __shfl_xor(s, off, 64);
            if (lane == 0) {
                ws[2] = s * (1.0f / (C_N * C_N));
                float s2 = 0.f;
#pragma unroll
                for (int c = 0; c < C_N; ++c) s2 += cnt_s[c] * cnt_s[c];
                ws[3] = (float)B_N * (float)B_N - s2;
            }
        }
        return;
    }

    // triangle decode: id-1 -> (bi, bj) with bj >= bi, bi-major
    int u = id - 1, bi = 0, rowlen = 32;
    while (u >= rowlen) { u -= rowlen; ++bi; --rowlen; }
    int bj = bi + u;

    int ib0 = bi * 128, jb0 = bj * 128;
    if (t < 128) lA[t] = labels[ib0 + t];
    else         lB[t - 128] = labels[jb0 + t - 128];
    if (t < C_N * C_N) topo_s[t] = topo[t];

    int quad = lane >> 4, m16 = lane & 15;
    int wrow = (w >> 1) * 64, wcol = (w & 1) * 64;

    f32x4 acc[4][4];
    f32x4 z = {0.f, 0.f, 0.f, 0.f};
#pragma unroll
    for (int mt = 0; mt < 4; ++mt)
#pragma unroll
        for (int nt = 0; nt < 4; ++nt) acc[mt][nt] = z;

    // staging: 8 chunks of 1KB per tile side per window (chunk = 16 rows x 64 B).
    // wave w owns chunks {w, w+4} per side.
    int rl = lane >> 2, cs = lane & 3;
    int csw = (cs ^ ((rl >> 1) & 3)) * 16;   // pre-swizzled global 16B slot
    const uchar* gA[2];
    const uchar* gB[2];
    int ldsoff[2];
#pragma unroll
    for (int h = 0; h < 2; ++h) {
        int chunk = w + 4 * h;
        gA[h] = E + (size_t)(ib0 + chunk * 16 + rl) * D_N + csw;
        gB[h] = E + (size_t)(jb0 + chunk * 16 + rl) * D_N + csw;
        ldsoff[h] = chunk * 1024;
    }

    // drain the scalar loads (labels/topo) so vmcnt counts ONLY window DMAs,
    // and make the lA/lB/topo_s LDS writes visible to all waves.
    asm volatile("s_waitcnt vmcnt(0) lgkmcnt(0)" ::: "memory");
    __builtin_amdgcn_s_barrier();
    __builtin_amdgcn_sched_barrier(0);

    // prologue: issue K-windows 0..2 (4 DMAs per thread per window, in order)
#pragma unroll
    for (int wv = 0; wv < 3; ++wv) {
#pragma unroll
        for (int h = 0; h < 2; ++h) {
            gl2lds16(gA[h] + wv * 64, smem + wv * 8192 + ldsoff[h]);
            gl2lds16(gB[h] + wv * 64, smem + 24576 + wv * 8192 + ldsoff[h]);
        }
    }

    int bufsel = 0;   // kt % 3
    for (int kt = 0; kt < 12; ++kt) {
        // counted wait: window kt's 4 DMAs done; deeper windows stay in flight
        if (kt < 10)       asm volatile("s_waitcnt vmcnt(8)" ::: "memory");
        else if (kt == 10) asm volatile("s_waitcnt vmcnt(4)" ::: "memory");
        else               asm volatile("s_waitcnt vmcnt(0)" ::: "memory");
        __builtin_amdgcn_s_barrier();
        __builtin_amdgcn_sched_barrier(0);

        const uchar* Ac = smem + bufsel * 8192;
        const uchar* Bc = smem + 24576 + bufsel * 8192;
#pragma unroll
        for (int ks = 0; ks < 2; ++ks) {
            int s = ks * 2 + (quad >> 1);   // 16B slot of this k-octet
            int in8 = (quad & 1) * 8;       // 8B half within the slot
            long af[4], bfr[4];
#pragma unroll
            for (int x = 0; x < 4; ++x) {
                int rowA = wrow + x * 16 + m16;
                int rowB = wcol + x * 16 + m16;
                af[x]  = *(const long*)(Ac + rowA * 64 + ((s ^ ((rowA >> 1) & 3)) * 16) + in8);
                bfr[x] = *(const long*)(Bc + rowB * 64 + ((s ^ ((rowB >> 1) & 3)) * 16) + in8);
            }
#pragma unroll
            for (int mt = 0; mt < 4; ++mt)
#pragma unroll
                for (int nt = 0; nt < 4; ++nt)
                    acc[mt][nt] = __builtin_amdgcn_mfma_f32_16x16x32_fp8_fp8(
                        af[mt], bfr[nt], acc[mt][nt], 0, 0, 0);
        }

        __builtin_amdgcn_sched_barrier(0);
        __builtin_amdgcn_s_barrier();   // all waves done reading buf[kt%3]
        if (kt + 3 < 12) {
#pragma unroll
            for (int h = 0; h < 2; ++h) {
                gl2lds16(gA[h] + (kt + 3) * 64, smem + bufsel * 8192 + ldsoff[h]);
                gl2lds16(gB[h] + (kt + 3) * 64, smem + 24576 + bufsel * 8192 + ldsoff[h]);
            }
        }
        bufsel = (bufsel == 2) ? 0 : bufsel + 1;
    }

    // epilogue: relu(sim - 1 + margin) over valid (li!=lj) upper-tri pairs, x2
    float local = 0.f;
#pragma unroll
    for (int mt = 0; mt < 4; ++mt) {
#pragma unroll
        for (int nt = 0; nt < 4; ++nt) {
#pragma unroll
            for (int reg = 0; reg < 4; ++reg) {
                int il = wrow + mt * 16 + quad * 4 + reg;
                int jl = wcol + nt * 16 + m16;
                int gi = ib0 + il, gj = jb0 + jl;
                int li = lA[il], lj = lB[jl];
                float v = acc[mt][nt][reg] - 1.0f + topo_s[li * C_N + lj];
                if (li != lj && gi < gj && v > 0.f) local += v;
            }
        }
    }
    local *= 2.0f;

#pragma unroll
    for (int off = 32; off; off >>= 1) local += __shfl_down(local, off, 64);
    if (lane == 0) wsum[w] = local;
    __syncthreads();
    // contention-spread partials: 8 slots across distinct dwords of one line region
    if (t == 0) atomicAdd(&ws[20 + (id & 7)], wsum[0] + wsum[1] + wsum[2] + wsum[3]);
}

// ---------------- final combine ----------------
__global__ void k_final(const float* __restrict__ ws, float* __restrict__ out) {
    if (threadIdx.x == 0 && blockIdx.x == 0) {
        float ce   = ws[0] / (float)B_N;
        float tals = ws[2];
        float tsum = 0.f;
#pragma unroll
        for (int i = 0; i < 8; ++i) tsum += ws[20 + i];
        float taml = tsum / fmaxf(ws[3], 1.0f);
        out[0] = ce + 0.5f * tals + 0.5f * taml;
        out[1] = ce;
        out[2] = tals;
        out[3] = taml;
    }
}

extern "C" void kernel_launch(void* const* d_in, const int* in_sizes, int n_in,
                              void* d_out, int out_size, void* d_ws, size_t ws_size,
                              hipStream_t stream) {
    const float* logits = (const float*)d_in[0];
    const int*   labels = (const int*)d_in[1];
    const float* emb    = (const float*)d_in[2];
    const float* topo   = (const float*)d_in[3];
    float* ws = (float*)d_ws;
    uchar* enorm = (uchar*)d_ws + 65536;
    float* out = (float*)d_out;

    hipMemsetAsync(d_ws, 0, 31232, stream);
    k_prep<<<1232, 256, 0, stream>>>(logits, labels, emb, ws, enorm);
    k_taml<<<529, 256, 0, stream>>>(enorm, labels, topo, ws);
    k_final<<<1, 64, 0, stream>>>(ws, out);
}